// Round 1
// baseline (716.167 us; speedup 1.0000x reference)
//
#include <hip/hip_runtime.h>
#include <hip/hip_bf16.h>

#define NPOS 49
#define NH 8
#define DIMC 384
#define VDC 512
#define SCALE_QK 0.17677669529663687f

typedef unsigned short u16;
typedef __attribute__((ext_vector_type(8))) short bf16x8_t;
typedef __attribute__((ext_vector_type(4))) float f32x4_t;

__device__ __forceinline__ u16 f2bf(float f) {
    unsigned u = __float_as_uint(f);
    u = (u + 0x7fffu + ((u >> 16) & 1u)) >> 16;
    return (u16)u;
}
__device__ __forceinline__ float bf2f(u16 b) {
    return __uint_as_float(((unsigned)b) << 16);
}

// Prep: fp32 -> bf16 weight conversion + bias table gather (ws re-poisoned each
// launch, so this must run every call; it does).
__global__ __launch_bounds__(256) void prep_kernel(
    const float* __restrict__ pw, const float* __restrict__ pj,
    const float* __restrict__ ab, const int* __restrict__ bidx,
    u16* __restrict__ wpw, u16* __restrict__ wpj, float* __restrict__ biasf)
{
    int i = blockIdx.x * 256 + threadIdx.x;
    if (i < 1024 * 384) wpw[i] = f2bf(pw[i]);
    if (i < 384 * 512)  wpj[i] = f2bf(pj[i]);
    if (i < 8 * 49 * 49) {
        int h = i / (49 * 49);
        int nm = i - h * (49 * 49);
        biasf[i] = ab[h * 49 + bidx[nm]];
    }
}

// One block per batch element. 512 threads = 8 waves.
// LDS (u16 units): region A [0, 31360): s_x [64][392] -> s_q [8*49][40] + s_k
//   (at 15680) -> s_P [8*49][72]; region B [31360, 68224): s_v [512][72] ->
//   s_out2 [rows][520]. Total 136,448 B.
__global__ __launch_bounds__(512) void fused_kernel(
    const float* __restrict__ x,
    const float* __restrict__ pwb,
    const float* __restrict__ dww,
    const float* __restrict__ bng, const float* __restrict__ bnb,
    const float* __restrict__ bnm, const float* __restrict__ bnv,
    const float* __restrict__ pjb,
    const u16* __restrict__ wpw, const u16* __restrict__ wpj,
    const float* __restrict__ biasf,
    float* __restrict__ out)
{
    __shared__ u16 lds[68224];
    const int tid  = threadIdx.x;
    const int b    = blockIdx.x;
    const int wv   = tid >> 6;
    const int lane = tid & 63;
    const int quad = lane >> 4;
    const int l16  = lane & 15;

    u16* s_x  = lds;            // [64][392] bf16 (rows 0..48 valid)
    u16* s_q  = lds;            // [(h*49+pos)][40], d in [0,32)
    u16* s_k  = lds + 15680;
    u16* s_P  = lds;            // [(h*49+q)][72], key in [0,64)
    u16* s_v  = lds + 31360;    // [512][72], pos in [0,49), pads zeroed
    u16* s_o2 = lds + 31360;    // [pos][520], c in [0,512)

    // ---- stage 0: x -> LDS bf16; zero s_v pad columns (NaN shield for PV) ----
    const float* xb = x + (size_t)b * (NPOS * DIMC);
    for (int i = tid; i < NPOS * DIMC; i += 512) {
        int n = i / DIMC;
        int c = i - n * DIMC;
        s_x[n * 392 + c] = f2bf(xb[i]);
    }
    for (int i = tid; i < 512 * 23; i += 512) {
        int c = i / 23, j = i - c * 23;
        s_v[c * 72 + 49 + j] = 0;
    }
    __syncthreads();

    // ---- stage 1: pwconv  h[1024][49] = W(1024x384) . x^T ----
    // A = x (M=pos), B = W^T (N=out-ch). Wave w owns channels [w*128, w*128+128).
    f32x4_t acc[8][4];
    #pragma unroll
    for (int nt = 0; nt < 8; ++nt)
        #pragma unroll
        for (int mt = 0; mt < 4; ++mt)
            acc[nt][mt] = (f32x4_t){0.f, 0.f, 0.f, 0.f};

    #pragma unroll
    for (int ks = 0; ks < 12; ++ks) {
        const int k0 = ks * 32 + quad * 8;
        bf16x8_t afr[4];
        #pragma unroll
        for (int mt = 0; mt < 4; ++mt)
            afr[mt] = *(const bf16x8_t*)(s_x + (mt * 16 + l16) * 392 + k0);
        #pragma unroll
        for (int nt = 0; nt < 8; ++nt) {
            const int och = wv * 128 + nt * 16 + l16;
            bf16x8_t bfr = *(const bf16x8_t*)(wpw + och * 384 + k0);
            #pragma unroll
            for (int mt = 0; mt < 4; ++mt)
                acc[nt][mt] = __builtin_amdgcn_mfma_f32_16x16x32_bf16(
                    afr[mt], bfr, acc[nt][mt], 0, 0, 0);
        }
    }
    __syncthreads();  // x dead; region A becomes q/k

    // D-write: +bias, route to q/k/v. D[row=quad*4+r+16mt][col=och].
    #pragma unroll
    for (int nt = 0; nt < 8; ++nt) {
        const int och = wv * 128 + nt * 16 + l16;
        const float bias = pwb[och];
        u16* dst;
        int stride;
        if (och < 256)      { dst = s_q + ((och >> 5) * 49) * 40 + (och & 31); stride = 40; }
        else if (och < 512) { int o2 = och - 256;
                              dst = s_k + ((o2 >> 5) * 49) * 40 + (o2 & 31); stride = 40; }
        else                { dst = s_v + (och - 512) * 72; stride = 1; }
        #pragma unroll
        for (int mt = 0; mt < 4; ++mt)
            #pragma unroll
            for (int r = 0; r < 4; ++r) {
                int pos = mt * 16 + quad * 4 + r;
                if (pos < 49) dst[pos * stride] = f2bf(acc[nt][mt][r] + bias);
            }
    }
    __syncthreads();

    // ---- stage 2: depthwise 3x3 + BN + exact GELU residual (thread = channel) ----
    {
        const int c = tid;
        u16* src = s_v + c * 72;
        float vv[49];
        #pragma unroll
        for (int i = 0; i < 49; ++i) vv[i] = bf2f(src[i]);
        float tap[9];
        #pragma unroll
        for (int j = 0; j < 9; ++j) tap[j] = dww[c * 9 + j];
        const float scale = bng[c] * rsqrtf(bnv[c] + 1e-5f);
        const float shift = bnb[c] - bnm[c] * scale;
        float res[49];
        #pragma unroll
        for (int y = 0; y < 7; ++y)
            #pragma unroll
            for (int xx = 0; xx < 7; ++xx) {
                float s = 0.f;
                #pragma unroll
                for (int ky = 0; ky < 3; ++ky)
                    #pragma unroll
                    for (int kx = 0; kx < 3; ++kx) {
                        int iy = y + ky - 1, ix = xx + kx - 1;
                        if (iy >= 0 && iy < 7 && ix >= 0 && ix < 7)
                            s += tap[ky * 3 + kx] * vv[iy * 7 + ix];
                    }
                s = s * scale + shift;
                float g = 0.5f * s * (1.0f + erff(s * 0.70710678118654752f));
                res[y * 7 + xx] = vv[y * 7 + xx] + g;
            }
        #pragma unroll
        for (int i = 0; i < 49; ++i) src[i] = f2bf(res[i]);
    }
    __syncthreads();

    // ---- stage 3: attention, wave = head ----
    {
        const int h = wv;
        bf16x8_t qa[4], kfr[4];
        #pragma unroll
        for (int mt = 0; mt < 4; ++mt)
            qa[mt] = *(const bf16x8_t*)(s_q + (h * 49 + mt * 16 + l16) * 40 + quad * 8);
        #pragma unroll
        for (int nt = 0; nt < 4; ++nt)
            kfr[nt] = *(const bf16x8_t*)(s_k + (h * 49 + nt * 16 + l16) * 40 + quad * 8);
        f32x4_t sc[4][4];
        #pragma unroll
        for (int mt = 0; mt < 4; ++mt)
            #pragma unroll
            for (int nt = 0; nt < 4; ++nt) {
                f32x4_t z = (f32x4_t){0.f, 0.f, 0.f, 0.f};
                sc[mt][nt] = __builtin_amdgcn_mfma_f32_16x16x32_bf16(qa[mt], kfr[nt], z, 0, 0, 0);
            }

        float pvreg[4][4][4];  // [mt][r][nt]
        #pragma unroll
        for (int mt = 0; mt < 4; ++mt)
            #pragma unroll
            for (int r = 0; r < 4; ++r) {
                const int qrow = mt * 16 + quad * 4 + r;
                float sv[4];
                #pragma unroll
                for (int nt = 0; nt < 4; ++nt) {
                    const int key = nt * 16 + l16;
                    float val = sc[mt][nt][r] * SCALE_QK;
                    if (key < 49 && qrow < 49) val += biasf[(h * 49 + qrow) * 49 + key];
                    else                       val = -1e30f;  // also kills stale-LDS NaN
                    sv[nt] = val;
                }
                float mx = fmaxf(fmaxf(sv[0], sv[1]), fmaxf(sv[2], sv[3]));
                #pragma unroll
                for (int off = 1; off < 16; off <<= 1)
                    mx = fmaxf(mx, __shfl_xor(mx, off));
                float e0 = __expf(sv[0] - mx), e1 = __expf(sv[1] - mx);
                float e2 = __expf(sv[2] - mx), e3 = __expf(sv[3] - mx);
                float sum = e0 + e1 + e2 + e3;
                #pragma unroll
                for (int off = 1; off < 16; off <<= 1)
                    sum += __shfl_xor(sum, off);
                const float inv = 1.0f / sum;
                pvreg[mt][r][0] = e0 * inv; pvreg[mt][r][1] = e1 * inv;
                pvreg[mt][r][2] = e2 * inv; pvreg[mt][r][3] = e3 * inv;
            }
        __syncthreads();  // all q/k reads done before P overwrites region A
        #pragma unroll
        for (int mt = 0; mt < 4; ++mt)
            #pragma unroll
            for (int r = 0; r < 4; ++r) {
                const int qrow = mt * 16 + quad * 4 + r;
                if (qrow < 49) {
                    #pragma unroll
                    for (int nt = 0; nt < 4; ++nt)
                        s_P[(h * 49 + qrow) * 72 + nt * 16 + l16] = f2bf(pvreg[mt][r][nt]);
                }
            }
        __syncthreads();

        // PV: out_h(49x64) = P(49x64keys) . V(64keys x 64)
        f32x4_t oa[4][4];
        #pragma unroll
        for (int mt = 0; mt < 4; ++mt)
            #pragma unroll
            for (int nt = 0; nt < 4; ++nt)
                oa[mt][nt] = (f32x4_t){0.f, 0.f, 0.f, 0.f};
        #pragma unroll
        for (int ksv = 0; ksv < 2; ++ksv) {
            const int kb0 = ksv * 32 + quad * 8;
            bf16x8_t pa[4], vb[4];
            #pragma unroll
            for (int mt = 0; mt < 4; ++mt)
                pa[mt] = *(const bf16x8_t*)(s_P + (h * 49 + mt * 16 + l16) * 72 + kb0);
            #pragma unroll
            for (int nt = 0; nt < 4; ++nt)
                vb[nt] = *(const bf16x8_t*)(s_v + (h * 64 + nt * 16 + l16) * 72 + kb0);
            #pragma unroll
            for (int mt = 0; mt < 4; ++mt)
                #pragma unroll
                for (int nt = 0; nt < 4; ++nt)
                    oa[mt][nt] = __builtin_amdgcn_mfma_f32_16x16x32_bf16(
                        pa[mt], vb[nt], oa[mt][nt], 0, 0, 0);
        }
        __syncthreads();  // all s_v reads done before out2 overwrites region B
        #pragma unroll
        for (int mt = 0; mt < 4; ++mt)
            #pragma unroll
            for (int nt = 0; nt < 4; ++nt)
                #pragma unroll
                for (int r = 0; r < 4; ++r) {
                    int pos = mt * 16 + quad * 4 + r;
                    if (pos < 49)
                        s_o2[pos * 520 + h * 64 + nt * 16 + l16] = f2bf(oa[mt][nt][r]);
                }
    }
    __syncthreads();

    // ---- stage 4: proj  out(49x384) = out2(49x512) . proj_w^T ----
    {
        f32x4_t pacc[3][4];
        #pragma unroll
        for (int ntl = 0; ntl < 3; ++ntl)
            #pragma unroll
            for (int mt = 0; mt < 4; ++mt)
                pacc[ntl][mt] = (f32x4_t){0.f, 0.f, 0.f, 0.f};
        #pragma unroll
        for (int ks = 0; ks < 16; ++ks) {
            const int k0 = ks * 32 + quad * 8;
            bf16x8_t afr[4];
            #pragma unroll
            for (int mt = 0; mt < 4; ++mt)
                afr[mt] = *(const bf16x8_t*)(s_o2 + (mt * 16 + l16) * 520 + k0);
            #pragma unroll
            for (int ntl = 0; ntl < 3; ++ntl) {
                const int o = (wv * 3 + ntl) * 16 + l16;
                bf16x8_t wb = *(const bf16x8_t*)(wpj + o * 512 + k0);
                #pragma unroll
                for (int mt = 0; mt < 4; ++mt)
                    pacc[ntl][mt] = __builtin_amdgcn_mfma_f32_16x16x32_bf16(
                        afr[mt], wb, pacc[ntl][mt], 0, 0, 0);
            }
        }
        float* ob = out + (size_t)b * (NPOS * DIMC);
        #pragma unroll
        for (int ntl = 0; ntl < 3; ++ntl) {
            const int o = (wv * 3 + ntl) * 16 + l16;
            const float pb = pjb[o];
            #pragma unroll
            for (int mt = 0; mt < 4; ++mt)
                #pragma unroll
                for (int r = 0; r < 4; ++r) {
                    int pos = mt * 16 + quad * 4 + r;
                    if (pos < 49) ob[pos * 384 + o] = pacc[ntl][mt][r] + pb;
                }
        }
    }
}

extern "C" void kernel_launch(void* const* d_in, const int* in_sizes, int n_in,
                              void* d_out, int out_size, void* d_ws, size_t ws_size,
                              hipStream_t stream)
{
    const float* x   = (const float*)d_in[0];
    const float* pw  = (const float*)d_in[1];
    const float* pwb = (const float*)d_in[2];
    const float* dww = (const float*)d_in[3];
    const float* bng = (const float*)d_in[4];
    const float* bnb = (const float*)d_in[5];
    const float* bnm = (const float*)d_in[6];
    const float* bnv = (const float*)d_in[7];
    const float* ab  = (const float*)d_in[8];
    const float* pj  = (const float*)d_in[9];
    const float* pjb = (const float*)d_in[10];
    const int*  bidx = (const int*)d_in[11];
    float* out = (float*)d_out;

    // ws layout: pwconv_w bf16 | proj_w bf16 | bias table fp32  (~1.26 MB)
    u16* wpw   = (u16*)d_ws;
    u16* wpj   = wpw + 1024 * 384;
    float* bia = (float*)(wpj + 384 * 512);

    const int nb = in_sizes[0] / (NPOS * DIMC);

    prep_kernel<<<1536, 256, 0, stream>>>(pw, pj, ab, bidx, wpw, wpj, bia);
    fused_kernel<<<nb, 512, 0, stream>>>(x, pwb, dww, bng, bnb, bnm, bnv, pjb,
                                         wpw, wpj, bia, out);
}